// Round 5
// baseline (111.767 us; speedup 1.0000x reference)
//
#include <hip/hip_runtime.h>

// Problem constants: B=8, N=128, T=64, EMBED=64, HEADS=8, HEAD_DIM=8
// V/K/Q/Out layout: (b, n, t, c) fp32, element strides (524288, 4096, 64, 1).
// History: 114.8 MFMA base -> R0 latency restructure NULL -> R1 reg diet -3.3
//   -> R2 MFMA-denominator softmax -0.5 -> R3 bank-conflict fix + weight
//   folding -0.8. Kernel ~25.5us vs ~16us serialized component model: the
//   gap is TLP (4 waves/SIMD, phases pay latency bare).
// R4 (this): 8 waves/SIMD. 1024-thread blocks (16 waves per (b,t)),
//   __launch_bounds__(1024,8) -> <=64 VGPR -> 32 waves/CU. Diet:
//   single-cell staging (24 regs in flight), MT read per-dp (uniform LDS
//   broadcast), attention wave=(head,q-half) with kf/vf re-read per strip
//   in groups of 4, fc 2 tiles/wave. LDS 76704B x2 = 150KB <= 160KB.

typedef _Float16 half4 __attribute__((ext_vector_type(4)));
typedef float    f32x4 __attribute__((ext_vector_type(4)));

#define MFMA16(a,b,c) __builtin_amdgcn_mfma_f32_16x16x16f16((a),(b),(c),0,0,0)

__device__ __forceinline__ unsigned short f2h(float f){
    union { _Float16 h; unsigned short u; } c; c.h = (_Float16)f; return c.u;
}
__device__ __forceinline__ float dot4(const float4 a, const float4 b){
    return a.x*b.x + a.y*b.y + a.z*b.z + a.w*b.w;
}

// LDS offsets in halves (ushort units). Total 38352 halves = 76704 B -> 2 blocks/CU.
#define ZS 0          //    8 halves zero scratch (b64-read target for padded lanes)
#define OS 8          //    8 halves ONES scratch (denominator column for PV)
#define MB 16         //  128 halves: MT f32 [8 d'][8 d] (M^T, SC folded)
#define KB 144        // KM per head: [128 k][8 d'], head stride 1024
#define QB 8336       // Q raw per head: [128 q][8 d'], head stride 1024
#define VB 16528      // V raw ^T per head: [8 d][136], head stride 1096
#define CB 25296      // C: [128 n][68]  (stride 68 -> conflict-free fc reads)
#define WB 34000      // W2 = Wo*blockdiag(Wv): [64 o][68]
#define LDS_TOTAL 38352

__global__ __launch_bounds__(1024, 8)
void sattn_kernel(const float* __restrict__ V,
                  const float* __restrict__ K,
                  const float* __restrict__ Q,
                  const float* __restrict__ Wv,
                  const float* __restrict__ Wk,
                  const float* __restrict__ Wq,
                  const float* __restrict__ Wo,
                  const float* __restrict__ bo,
                  float* __restrict__ Out)
{
    __shared__ __align__(16) unsigned short smem[LDS_TOTAL];

    const int tid  = threadIdx.x;          // 0..1023
    const int bid  = blockIdx.x;
    const int b    = bid >> 6;
    const int t    = bid & 63;
    const long base = (long)b * 524288 + t * 64;
    const float SC = 0.18033688011112043f;   // (1/8) * log2(e), folded into M

    const int cn = tid >> 3;   // 0..127  (one staging cell per thread)
    const int ch = tid & 7;

    // ---- issue this thread's 6 input float4 loads up-front ----
    const float* p0 = K + base + cn*4096 + ch*8;
    const float* p1 = V + base + cn*4096 + ch*8;
    const float* p2 = Q + base + cn*4096 + ch*8;
    float4 ka = *(const float4*)p0, kb = *(const float4*)(p0+4);
    float4 va = *(const float4*)p1, vb_ = *(const float4*)(p1+4);
    float4 qa = *(const float4*)p2, qb_ = *(const float4*)(p2+4);

    // ---- zero scratch + ones scratch ----
    if (tid < 4)      *(unsigned int*)(smem + tid*2) = 0u;
    else if (tid < 8) *(unsigned int*)(smem + tid*2) = 0x3C003C00u;  // {1.0h,1.0h}

    // ---- build W2 = Wo * blockdiag(Wv x8), f16 [64 o][68] (tid < 512) ----
    if (tid < 512){
        const int o = tid >> 3, g = tid & 7;
        const float* ws = Wo + o*64 + g*8;
        float4 woa = *(const float4*)ws;
        float4 wob = *(const float4*)(ws + 4);
        float wo8[8] = {woa.x, woa.y, woa.z, woa.w, wob.x, wob.y, wob.z, wob.w};
        float w2[8] = {0,0,0,0,0,0,0,0};
        #pragma unroll
        for (int e = 0; e < 8; ++e){
            float4 wv0 = *(const float4*)(Wv + e*8);   // uniform -> s_load
            float4 wv1 = *(const float4*)(Wv + e*8 + 4);
            float we = wo8[e];
            w2[0] += we*wv0.x; w2[1] += we*wv0.y; w2[2] += we*wv0.z; w2[3] += we*wv0.w;
            w2[4] += we*wv1.x; w2[5] += we*wv1.y; w2[6] += we*wv1.z; w2[7] += we*wv1.w;
        }
        half4 h0; h0.x=(_Float16)w2[0]; h0.y=(_Float16)w2[1]; h0.z=(_Float16)w2[2]; h0.w=(_Float16)w2[3];
        half4 h1; h1.x=(_Float16)w2[4]; h1.y=(_Float16)w2[5]; h1.z=(_Float16)w2[6]; h1.w=(_Float16)w2[7];
        *(half4*)(smem + WB + o*68 + g*8)     = h0;
        *(half4*)(smem + WB + o*68 + g*8 + 4) = h1;
    }

    // ---- build MT[d'][d] = SC * sum_e Wk[e][d]*Wq[e][d'], f32 in LDS ----
    if (tid < 64){
        const int dd = tid & 7;    // d  (Wk column)
        const int dp = tid >> 3;   // d' (Wq column)
        float m = 0.f;
        #pragma unroll
        for (int e = 0; e < 8; ++e)
            m += Wk[e*8 + dd] * Wq[e*8 + dp];
        reinterpret_cast<float*>(smem + MB)[tid] = m * SC;   // MT[dp][dd]
    }

    // ---- stage RAW Q (f2h only): [128 q][8 d'], head stride 1024 ----
    {
        half4 h0; h0.x=(_Float16)qa.x; h0.y=(_Float16)qa.y; h0.z=(_Float16)qa.z; h0.w=(_Float16)qa.w;
        half4 h1; h1.x=(_Float16)qb_.x; h1.y=(_Float16)qb_.y; h1.z=(_Float16)qb_.z; h1.w=(_Float16)qb_.w;
        *(half4*)(smem + QB + ch*1024 + cn*8)     = h0;
        *(half4*)(smem + QB + ch*1024 + cn*8 + 4) = h1;
    }

    // ---- stage RAW V transposed: [8 d][136], head stride 1096 ----
    // write bank = (4ch + 4d + cn/2) mod 32 -> 2 lanes/bank (free)
    {
        unsigned short* vb = smem + VB + ch*1096;
        vb[0*136 + cn] = f2h(va.x); vb[1*136 + cn] = f2h(va.y);
        vb[2*136 + cn] = f2h(va.z); vb[3*136 + cn] = f2h(va.w);
        vb[4*136 + cn] = f2h(vb_.x); vb[5*136 + cn] = f2h(vb_.y);
        vb[6*136 + cn] = f2h(vb_.z); vb[7*136 + cn] = f2h(vb_.w);
    }

    __syncthreads();   // MT ready

    // ---- project K by MT: KM[k][d'] = sum_d K[k][d]*MT[d'][d] ----
    // MT reads are wave-uniform -> LDS broadcast (conflict-free, low regs)
    {
        const float* mt = reinterpret_cast<const float*>(smem + MB);
        float ok[8];
        #pragma unroll
        for (int dp = 0; dp < 8; ++dp){
            float4 m0 = *(const float4*)(mt + dp*8);
            float4 m1 = *(const float4*)(mt + dp*8 + 4);
            ok[dp] = dot4(ka, m0) + dot4(kb, m1);
        }
        half4 h0; h0.x=(_Float16)ok[0]; h0.y=(_Float16)ok[1]; h0.z=(_Float16)ok[2]; h0.w=(_Float16)ok[3];
        half4 h1; h1.x=(_Float16)ok[4]; h1.y=(_Float16)ok[5]; h1.z=(_Float16)ok[6]; h1.w=(_Float16)ok[7];
        *(half4*)(smem + KB + ch*1024 + cn*8)     = h0;
        *(half4*)(smem + KB + ch*1024 + cn*8 + 4) = h1;
    }

    __syncthreads();

    // ---- attention: wave = (head, q-half). 16 waves, 4 strips each ----
    const int wid  = tid >> 6;          // 0..15
    const int h    = wid >> 1;
    const int qh   = wid & 1;
    const int lane = tid & 63;
    const int q16  = lane & 15;
    const int quad = lane >> 4;
    const f32x4 zz = {0.f, 0.f, 0.f, 0.f};

    #pragma unroll 1
    for (int qs4 = 0; qs4 < 4; ++qs4){
        const int qs = qh*4 + qs4;

        // Qraw B-fragment: B[k=d'][n=q], quads 2,3 -> zero
        int qadr = QB + h*1024 + (qs*16 + q16)*8 + quad*4;
        if (quad >= 2) qadr = ZS;
        half4 qf = *(const half4*)(smem + qadr);

        half4 pf[8];

        // E^T group A (mt 0..3): read kf, 4 MFMAs, exp2+pack
        {
            half4 kfa[4];
            #pragma unroll
            for (int mt = 0; mt < 4; ++mt){
                int a = KB + h*1024 + (mt*16 + q16)*8 + quad*4;
                if (quad >= 2) a = ZS;
                kfa[mt] = *(const half4*)(smem + a);
            }
            f32x4 acc[4];
            #pragma unroll
            for (int mt = 0; mt < 4; ++mt)
                acc[mt] = MFMA16(kfa[mt], qf, zz);
            #pragma unroll
            for (int mt = 0; mt < 4; ++mt){
                pf[mt].x = (_Float16)__builtin_amdgcn_exp2f(acc[mt][0]);
                pf[mt].y = (_Float16)__builtin_amdgcn_exp2f(acc[mt][1]);
                pf[mt].z = (_Float16)__builtin_amdgcn_exp2f(acc[mt][2]);
                pf[mt].w = (_Float16)__builtin_amdgcn_exp2f(acc[mt][3]);
            }
        }
        // E^T group B (mt 4..7)
        {
            half4 kfa[4];
            #pragma unroll
            for (int mt = 0; mt < 4; ++mt){
                int a = KB + h*1024 + ((mt+4)*16 + q16)*8 + quad*4;
                if (quad >= 2) a = ZS;
                kfa[mt] = *(const half4*)(smem + a);
            }
            f32x4 acc[4];
            #pragma unroll
            for (int mt = 0; mt < 4; ++mt)
                acc[mt] = MFMA16(kfa[mt], qf, zz);
            #pragma unroll
            for (int mt = 0; mt < 4; ++mt){
                pf[mt+4].x = (_Float16)__builtin_amdgcn_exp2f(acc[mt][0]);
                pf[mt+4].y = (_Float16)__builtin_amdgcn_exp2f(acc[mt][1]);
                pf[mt+4].z = (_Float16)__builtin_amdgcn_exp2f(acc[mt][2]);
                pf[mt+4].w = (_Float16)__builtin_amdgcn_exp2f(acc[mt][3]);
            }
        }

        // PV: two 4-deep chains, vf read per group. Column d=8 (ones)
        // accumulates the softmax denominator in the matrix pipe.
        f32x4 o0 = zz, o1 = zz;
        {
            half4 vfa[4];
            #pragma unroll
            for (int s = 0; s < 4; ++s){
                int a = VB + h*1096 + q16*136 + s*16 + quad*4;
                if (q16 > 8)  a = ZS;
                if (q16 == 8) a = OS;
                vfa[s] = *(const half4*)(smem + a);
            }
            #pragma unroll
            for (int s = 0; s < 4; ++s)
                o0 = MFMA16(pf[s], vfa[s], o0);
        }
        {
            half4 vfa[4];
            #pragma unroll
            for (int s = 0; s < 4; ++s){
                int a = VB + h*1096 + q16*136 + (s+4)*16 + quad*4;
                if (q16 > 8)  a = ZS;
                if (q16 == 8) a = OS;
                vfa[s] = *(const half4*)(smem + a);
            }
            #pragma unroll
            for (int s = 0; s < 4; ++s)
                o1 = MFMA16(pf[s+4], vfa[s], o1);
        }

        float tr[4];
        #pragma unroll
        for (int r = 0; r < 4; ++r)
            tr[r] = o0[r] + o1[r];

        // inv per output row q=quad*4+r lives at lane (quad*16 + 8)
        const int dl = (lane & 48) + 8;
        float invr[4];
        #pragma unroll
        for (int r = 0; r < 4; ++r)
            invr[r] = __builtin_amdgcn_rcpf(__shfl(tr[r], dl, 64));

        // write C strip: lane holds out[q=quad*4+r][d=l&15<8]
        if (q16 < 8){
            #pragma unroll
            for (int r = 0; r < 4; ++r){
                int row = qs*16 + quad*4 + r;
                smem[CB + row*68 + h*8 + q16] = f2h(tr[r] * invr[r]);
            }
        }
    }

    __syncthreads();

    // ---- fc with W2: 32 tiles (8 row x 4 col) / 16 waves = 2 tiles each ----
    const int rt  = wid >> 1;           // row tile 0..7
    const int ntb = (wid & 1) * 2;      // col tile base

    half4 af[4];
    #pragma unroll
    for (int ks = 0; ks < 4; ++ks)
        af[ks] = *(const half4*)(smem + CB + (rt*16 + q16)*68 + ks*16 + quad*4);

    #pragma unroll
    for (int j = 0; j < 2; ++j){
        const int nt = ntb + j;
        f32x4 a = zz;
        #pragma unroll
        for (int ks = 0; ks < 4; ++ks){
            half4 bf = *(const half4*)(smem + WB + (nt*16 + q16)*68 + ks*16 + quad*4);
            a = MFMA16(af[ks], bf, a);
        }
        float bb = bo[nt*16 + q16];
        #pragma unroll
        for (int r = 0; r < 4; ++r){
            int row = rt*16 + quad*4 + r;
            Out[base + (long)row*4096 + nt*16 + q16] = a[r] + bb;
        }
    }
}

extern "C" void kernel_launch(void* const* d_in, const int* in_sizes, int n_in,
                              void* d_out, int out_size, void* d_ws, size_t ws_size,
                              hipStream_t stream)
{
    const float* V  = (const float*)d_in[0];
    const float* K  = (const float*)d_in[1];
    const float* Q  = (const float*)d_in[2];
    const float* Wv = (const float*)d_in[3];
    const float* Wk = (const float*)d_in[4];
    const float* Wq = (const float*)d_in[5];
    const float* Wo = (const float*)d_in[6];
    const float* bo = (const float*)d_in[7];

    sattn_kernel<<<dim3(512), dim3(1024), 0, stream>>>(
        V, K, Q, Wv, Wk, Wq, Wo, bo, (float*)d_out);
}